// Round 12
// baseline (134.610 us; speedup 1.0000x reference)
//
#include <hip/hip_runtime.h>
#include <math.h>

// Problem constants
#define HW 4096
#define C 320
#define CX 768
#define L 77
#define NB 10
#define NH 8
#define HD 40
#define NINST 8
#define KVC 640
#define SCALE 0.15811388300841898f  // 1/sqrt(40)
#define PSTR 104                    // P LDS row stride in halves
#define KSTR 48                     // staged K row stride (halves, 16B-aligned)
#define VSTR 104                    // staged V row stride (halves, 16B-aligned)

typedef _Float16 half8v __attribute__((ext_vector_type(8)));
typedef _Float16 half4v __attribute__((ext_vector_type(4)));
typedef float f32x4 __attribute__((ext_vector_type(4)));

// per-(b,h) packed sizes in halves
#define KBH (80 * KSTR)             // 3840
#define VBH (48 * VSTR)             // 4992

// prep grid segmentation
#define SEG_MASK   16
#define N_CVT1     (2 * HW * C / 4)
#define N_CVT2     (NB * L * CX / 4)
#define SEG_CVT    (((N_CVT1 + N_CVT2) + 255) / 256)  // 3138
#define SEG_WPACK  240
#define SEG_VTZ    195                 // 80*VBH/8/256 = 49920/256
#define SEG_KPAD   6                   // 80*3*KSTR/8 = 1440 chunks
#define NPREP      (SEG_MASK + SEG_CVT + SEG_WPACK + SEG_VTZ + SEG_KPAD)

// ---------------------------------------------------------------------------
// prep: maskw + cvt + weight packs + VTg init (zeros + ones-row at d=40)
// + Khp pad-key-row zeroing, one dispatch.
// ---------------------------------------------------------------------------
__device__ __forceinline__ float axis_profile(int o, float lo, float hi) {
    float num = 0.f, den = 0.f;
    int j0 = 8 * o - 4;
#pragma unroll
    for (int t = 0; t < 16; ++t) {
        int j = j0 + t;
        float wt = 1.0f - fabsf((float)t - 7.5f) * 0.125f;
        if (j >= 0 && j < 512) {
            den += wt;
            float fj = (float)j;
            if (fj >= lo && fj < hi) num += wt;
        }
    }
    return num / den;
}

__global__ __launch_bounds__(256) void prep_kernel(
        const float* __restrict__ bboxes,
        const float* __restrict__ hs, const float* __restrict__ ehs,
        const float* __restrict__ Wq, const float* __restrict__ Wk,
        const float* __restrict__ Wv, const float* __restrict__ Wo,
        float* __restrict__ wPh, float* __restrict__ wSum,
        _Float16* __restrict__ hsH, _Float16* __restrict__ ehsH,
        _Float16* __restrict__ WqT, _Float16* __restrict__ WkvT,
        _Float16* __restrict__ WoT, _Float16* __restrict__ VTg,
        _Float16* __restrict__ Khp) {
    __shared__ float tile[64][65];
    __shared__ float sw_s[NINST][64];
    __shared__ float sh_s[NINST][4];
    int bx = blockIdx.x, tid = threadIdx.x;

    if (bx < SEG_MASK) {
        int oyb = bx * 4;
        for (int i = tid; i < NINST * 64; i += 256) {
            int n = i >> 6, ox = i & 63;
            float lo = floorf(512.f * bboxes[n * 4 + 0]);
            float hi = floorf(512.f * bboxes[n * 4 + 2]);
            sw_s[n][ox] = axis_profile(ox, lo, hi);
        }
        if (tid < NINST * 4) {
            int n = tid >> 2, oy = tid & 3;
            float lo = floorf(512.f * bboxes[n * 4 + 1]);
            float hi = floorf(512.f * bboxes[n * 4 + 3]);
            sh_s[n][oy] = axis_profile(oyb + oy, lo, hi);
        }
        __syncthreads();
        int oy = tid >> 6, ox = tid & 63;
        int hw = (oyb + oy) * 64 + ox;
        float sum = 0.1f;
        wPh[hw] = 0.1f;
#pragma unroll
        for (int n = 0; n < NINST; ++n) {
            float wv = 10.f * sh_s[n][oy] * sw_s[n][ox];
            wPh[(n + 1) * HW + hw] = wv;
            sum += wv;
        }
        wSum[hw] = sum;
    } else if (bx < SEG_MASK + SEG_CVT) {
        int i = (bx - SEG_MASK) * 256 + tid;
        const float* src; _Float16* dst;
        if (i < N_CVT1) { src = hs; dst = hsH; }
        else if (i < N_CVT1 + N_CVT2) { i -= N_CVT1; src = ehs; dst = ehsH; }
        else return;
        float4 v = ((const float4*)src)[i];
        half4v h = {(_Float16)v.x, (_Float16)v.y, (_Float16)v.z, (_Float16)v.w};
        ((half4v*)dst)[i] = h;
    } else if (bx < SEG_MASK + SEG_CVT + SEG_WPACK) {
        int zz = bx - SEG_MASK - SEG_CVT;
        int z = zz / 60, inner = zz - z * 60;
        int by = inner / 5, bx2 = inner - by * 5;
        const float* W; _Float16* WT; int K;
        if (z == 0)      { W = Wq; WT = WqT; K = C; }
        else if (z == 1) { W = Wk; WT = WkvT; K = CX; }
        else if (z == 2) { W = Wv; WT = WkvT + (size_t)C * CX; K = CX; }
        else             { W = Wo; WT = WoT; K = C; }
        int kt = by * 64;
        if (kt >= K) return;
        int nt = bx2 * 64;
#pragma unroll
        for (int p = 0; p < 16; ++p) {
            int idx = p * 256 + tid;
            int k = idx >> 6, n = idx & 63;
            tile[k][n] = W[(size_t)(kt + k) * C + nt + n];
        }
        __syncthreads();
#pragma unroll
        for (int p = 0; p < 16; ++p) {
            int idx = p * 256 + tid;
            int n = idx >> 6, k = idx & 63;
            WT[(size_t)(nt + n) * K + kt + k] = (_Float16)tile[k][n];
        }
    } else if (bx < SEG_MASK + SEG_CVT + SEG_WPACK + SEG_VTZ) {
        // VTg init (stride VSTR): zeros; d==40 row = 1.0 for key<77
        int i = (bx - SEG_MASK - SEG_CVT - SEG_WPACK) * 256 + tid;  // half8 idx
        int e0 = i * 8;
        int rem = e0 % VBH;
        int d = rem / VSTR;
        int key0 = rem % VSTR;
        half8v v;
#pragma unroll
        for (int j = 0; j < 8; ++j)
            v[j] = (_Float16)((d == 40 && (key0 + j) < 77) ? 1.f : 0.f);
        ((half8v*)VTg)[i] = v;
    } else {
        // Khp pad key rows 77..79 per (b,h) = 0
        int i = (bx - SEG_MASK - SEG_CVT - SEG_WPACK - SEG_VTZ) * 256 + tid;
        if (i < 1440) {
            int rowIdx = i / 6, c8 = i - rowIdx * 6;   // 6 half8 per KSTR row
            int bh = rowIdx / 3;
            int key = 77 + rowIdx - bh * 3;
            half8v z8 = {(_Float16)0.f,(_Float16)0.f,(_Float16)0.f,(_Float16)0.f,
                         (_Float16)0.f,(_Float16)0.f,(_Float16)0.f,(_Float16)0.f};
            *(half8v*)(Khp + ((size_t)bh * 80 + key) * KSTR + c8 * 8) = z8;
        }
    }
}

// ---------------------------------------------------------------------------
// K/V projection. K half -> Khp[b][h][key][KSTR]; V half -> VTg transposed.
// A-fragments (K=768: 24 half8) preloaded in one burst -> per-k chain is
// B loads + MFMA only (r12: only 130 blocks, VGPR budget free).
// ---------------------------------------------------------------------------
__global__ __launch_bounds__(256) void gemm_kv(const _Float16* __restrict__ A,
                                               const _Float16* __restrict__ BT,
                                               _Float16* __restrict__ Khp,
                                               _Float16* __restrict__ VTg) {
    const int K = CX, M = NB * L;
    int lane = threadIdx.x & 63, wave = threadIdx.x >> 6;
    int m0 = blockIdx.y * 64 + wave * 16;
    int n0 = blockIdx.x * 64;
    int lr = lane & 15, kq = (lane >> 4) * 8;
    int arow = m0 + lr; if (arow >= M) arow = M - 1;
    const _Float16* ap = A + (size_t)arow * K + kq;
    const _Float16* bp = BT + (size_t)(n0 + lr) * K + kq;

    half8v afr[24];
#pragma unroll
    for (int i = 0; i < 24; ++i) afr[i] = *(const half8v*)(ap + i * 32);

    f32x4 acc0 = {0.f,0.f,0.f,0.f}, acc1 = acc0, acc2 = acc0, acc3 = acc0;
#pragma unroll
    for (int i = 0; i < 24; ++i) {
        int k0 = i * 32;
        half8v b0 = *(const half8v*)(bp + k0);
        half8v b1 = *(const half8v*)(bp + (size_t)16 * K + k0);
        half8v b2 = *(const half8v*)(bp + (size_t)32 * K + k0);
        half8v b3 = *(const half8v*)(bp + (size_t)48 * K + k0);
        acc0 = __builtin_amdgcn_mfma_f32_16x16x32_f16(afr[i], b0, acc0, 0, 0, 0);
        acc1 = __builtin_amdgcn_mfma_f32_16x16x32_f16(afr[i], b1, acc1, 0, 0, 0);
        acc2 = __builtin_amdgcn_mfma_f32_16x16x32_f16(afr[i], b2, acc2, 0, 0, 0);
        acc3 = __builtin_amdgcn_mfma_f32_16x16x32_f16(afr[i], b3, acc3, 0, 0, 0);
    }
    int rb = m0 + ((lane >> 4) << 2);
    f32x4 accs[4] = {acc0, acc1, acc2, acc3};
#pragma unroll
    for (int t = 0; t < 4; ++t) {
        int col = n0 + t * 16 + lr;
#pragma unroll
        for (int r = 0; r < 4; ++r) {
            int row = rb + r;
            if (row < M) {
                int bb = row / 77;
                int key = row - bb * 77;
                if (col < C) {
                    int h = col / HD, d = col - h * HD;
                    Khp[((size_t)(bb * 8 + h) * 80 + key) * KSTR + d] = (_Float16)accs[t][r];
                } else {
                    int ch = col - C;
                    int h = ch / HD, d = ch - h * HD;
                    VTg[((size_t)(bb * 8 + h) * 48 + d) * VSTR + key] = (_Float16)accs[t][r];
                }
            }
        }
    }
}

// ---------------------------------------------------------------------------
// MFMA attention: transposed dataflow + block-level double-buffered LDS K/V
// staging (r11). r12: wPh weights for all 9 cond batches hoisted into
// registers before the loop (one coalesced burst vs per-batch loads).
// ---------------------------------------------------------------------------
__global__ __launch_bounds__(256, 2) void attn_mfma(const _Float16* __restrict__ hsH,  // (8192,320)
                                                    const _Float16* __restrict__ WqT,  // (320,320)
                                                    const _Float16* __restrict__ Khp,  // (80,80,KSTR)
                                                    const _Float16* __restrict__ VTg,  // (80,48,VSTR)
                                                    const float* __restrict__ wPh,     // (9,HW)
                                                    _Float16* __restrict__ Xh) {       // (8192,320)
    __shared__ _Float16 smem[2 * (KBH + VBH) + 4 * 2 * 16 * PSTR];
    _Float16* Ks0 = smem;
    _Float16* Vs0 = smem + KBH;
    _Float16* Ks1 = smem + KBH + VBH;
    _Float16* Vs1 = smem + 2 * KBH + VBH;
    _Float16* pbase = smem + 2 * (KBH + VBH);

    int tid = threadIdx.x;
    int wave = tid >> 6, lane = tid & 63;
    int head = blockIdx.x >> 6;
    int qg = blockIdx.x & 63;
    int qrow0 = qg * 64 + wave * 16;
    int c = lane & 15, quad = lane >> 4;
    _Float16* pl0 = pbase + (size_t)(wave * 2) * 16 * PSTR;
    _Float16* pl1 = pl0 + 16 * PSTR;
    half8v zero8 = {(_Float16)0.f,(_Float16)0.f,(_Float16)0.f,(_Float16)0.f,
                    (_Float16)0.f,(_Float16)0.f,(_Float16)0.f,(_Float16)0.f};

    const half8v* Kg8 = (const half8v*)(Khp + (size_t)head * KBH);
    const half8v* Vg8 = (const half8v*)(VTg + (size_t)head * VBH);

    // issue batch-0 stage loads (consumed after phase 1)
    half8v kr0, kr1, vr0, vr1, vr2;
    kr0 = Kg8[tid];
    if (tid < 224) kr1 = Kg8[tid + 256];
    vr0 = Vg8[tid];
    vr1 = Vg8[tid + 256];
    if (tid < 112) vr2 = Vg8[tid + 512];

    // hoist all 9 phase weights (one coalesced burst)
    float wreg[9];
#pragma unroll
    for (int j = 0; j < 9; ++j)
        wreg[j] = wPh[(size_t)j * HW + qrow0 + c];

    // zero P-buf cols 40..95 (Q pad + P pad keys 80..95)
#pragma unroll
    for (int i = 0; i < 4; ++i) {
        int idx = i * 64 + lane;
        if (idx < 224) {
            int buf = idx / 112;
            int rem = idx - buf * 112;
            int row = rem / 7, ch = rem - row * 7;
            _Float16* pb = buf ? pl1 : pl0;
            *(half8v*)&pb[row * PSTR + 40 + ch * 8] = zero8;
        }
    }

    // ---- Phase 1: Q^T projection (A=WqT rows d, B=hs rows qrow), SCALE folded ----
    {
        const _Float16* bu = hsH + (size_t)(qrow0 + c) * C + quad * 8;
        const _Float16* bc = bu + (size_t)HW * C;
        f32x4 qa0[3] = {}, qa1[3] = {};
        for (int k0 = 0; k0 < C; k0 += 32) {
            half8v hu = *(const half8v*)(bu + k0);
            half8v hc = *(const half8v*)(bc + k0);
#pragma unroll
            for (int t = 0; t < 3; ++t) {
                const _Float16* ap = WqT + (size_t)(head * HD + t * 16 + c) * C + quad * 8 + k0;
                half8v af = *(const half8v*)ap;
                qa0[t] = __builtin_amdgcn_mfma_f32_16x16x32_f16(af, hu, qa0[t], 0, 0, 0);
                qa1[t] = __builtin_amdgcn_mfma_f32_16x16x32_f16(af, hc, qa1[t], 0, 0, 0);
            }
        }
#pragma unroll
        for (int t = 0; t < 3; ++t) {
            if (t < 2 || quad < 2) {
                half4v h0 = {(_Float16)(qa0[t][0] * SCALE), (_Float16)(qa0[t][1] * SCALE),
                             (_Float16)(qa0[t][2] * SCALE), (_Float16)(qa0[t][3] * SCALE)};
                half4v h1 = {(_Float16)(qa1[t][0] * SCALE), (_Float16)(qa1[t][1] * SCALE),
                             (_Float16)(qa1[t][2] * SCALE), (_Float16)(qa1[t][3] * SCALE)};
                *(half4v*)(pl0 + c * PSTR + t * 16 + quad * 4) = h0;
                *(half4v*)(pl1 + c * PSTR + t * 16 + quad * 4) = h1;
            }
        }
    }
    // intra-wave LDS RAW: in-order DS pipe + compiler waitcnt (r5-r11 verified)
    half8v qu0 = *(const half8v*)(pl0 + (size_t)c * PSTR + quad * 8);
    half8v qu1 = *(const half8v*)(pl0 + (size_t)c * PSTR + 32 + quad * 8);
    half8v qc0 = *(const half8v*)(pl1 + (size_t)c * PSTR + quad * 8);
    half8v qc1 = *(const half8v*)(pl1 + (size_t)c * PSTR + 32 + quad * 8);

    // write staged batch-0 into buffer 0
    {
        half8v* Kd = (half8v*)Ks0;
        half8v* Vd = (half8v*)Vs0;
        Kd[tid] = kr0;
        if (tid < 224) Kd[tid + 256] = kr1;
        Vd[tid] = vr0;
        Vd[tid + 256] = vr1;
        if (tid < 112) Vd[tid + 512] = vr2;
    }
    __syncthreads();

    f32x4 oacc[3] = {};
    int srcl = 32 + c;   // lane holding O^T row d=40 (denominator) for qrow c

    for (int b = 0; b < NB; ++b) {
        // ---- issue next batch's stage loads ----
        if (b + 1 < NB) {
            const half8v* Kn = Kg8 + (size_t)(b + 1) * 8 * (KBH / 8);
            const half8v* Vn = Vg8 + (size_t)(b + 1) * 8 * (VBH / 8);
            kr0 = Kn[tid];
            if (tid < 224) kr1 = Kn[tid + 256];
            vr0 = Vn[tid];
            vr1 = Vn[tid + 256];
            if (tid < 112) vr2 = Vn[tid + 512];
        }

        _Float16* Kb = (b & 1) ? Ks1 : Ks0;
        _Float16* Vb = (b & 1) ? Vs1 : Vs0;
        half8v qb0 = b ? qc0 : qu0;
        half8v qb1 = b ? qc1 : qu1;
        float w = b ? wreg[b - 1] : 1.f;

        // ---- QK^T: A=K rows (key), B=Q ----
        f32x4 s[5];
#pragma unroll
        for (int u = 0; u < 5; ++u) {
            half8v ka0 = *(const half8v*)&Kb[(u * 16 + c) * KSTR + quad * 8];
            half8v ka1 = *(const half8v*)&Kb[(u * 16 + c) * KSTR + 32 + quad * 8];
            f32x4 a = {0.f,0.f,0.f,0.f};
            a = __builtin_amdgcn_mfma_f32_16x16x32_f16(ka0, qb0, a, 0, 0, 0);
            a = __builtin_amdgcn_mfma_f32_16x16x32_f16(ka1, qb1, a, 0, 0, 0);
            s[u] = a;
        }

        // ---- exp + P^T -> LDS ----
#pragma unroll
        for (int u = 0; u < 5; ++u) {
            half4v h = {(_Float16)__expf(s[u][0]), (_Float16)__expf(s[u][1]),
                        (_Float16)__expf(s[u][2]), (_Float16)__expf(s[u][3])};
            *(half4v*)(pl0 + c * PSTR + u * 16 + quad * 4) = h;
        }
        half8v p0 = *(const half8v*)(pl0 + (size_t)c * PSTR + quad * 8);
        half8v p1 = *(const half8v*)(pl0 + (size_t)c * PSTR + 32 + quad * 8);
        half8v p2 = *(const half8v*)(pl0 + (size_t)c * PSTR + 64 + quad * 8);

        // ---- PV: A=V^T rows (d), B=P^T ----
        f32x4 ox[3];
#pragma unroll
        for (int t = 0; t < 3; ++t) {
            half8v va0 = *(const half8v*)&Vb[(t * 16 + c) * VSTR + quad * 8];
            half8v va1 = *(const half8v*)&Vb[(t * 16 + c) * VSTR + 32 + quad * 8];
            half8v va2 = *(const half8v*)&Vb[(t * 16 + c) * VSTR + 64 + quad * 8];
            f32x4 a = {0.f,0.f,0.f,0.f};
            a = __builtin_amdgcn_mfma_f32_16x16x32_f16(va0, p0, a, 0, 0, 0);
            a = __builtin_amdgcn_mfma_f32_16x16x32_f16(va1, p1, a, 0, 0, 0);
            a = __builtin_amdgcn_mfma_f32_16x16x32_f16(va2, p2, a, 0, 0, 0);
            ox[t] = a;
        }

        float l = __shfl(ox[2][0], srcl, 64);

        if (b == 0) {
            float rin = 1.0f / l;
#pragma unroll
            for (int t = 0; t < 3; ++t) {
                if (t < 2 || quad < 2) {
                    half4v h = {(_Float16)(ox[t][0] * rin), (_Float16)(ox[t][1] * rin),
                                (_Float16)(ox[t][2] * rin), (_Float16)(ox[t][3] * rin)};
                    *(half4v*)(Xh + (size_t)(qrow0 + c) * C + head * HD + t * 16 + quad * 4) = h;
                }
            }
        } else {
            float rf = w / l;
#pragma unroll
            for (int t = 0; t < 3; ++t) {
                oacc[t][0] += ox[t][0] * rf;
                oacc[t][1] += ox[t][1] * rf;
                oacc[t][2] += ox[t][2] * rf;
                oacc[t][3] += ox[t][3] * rf;
            }
        }

        // ---- write next batch into the other buffer ----
        if (b + 1 < NB) {
            half8v* Kd = (half8v*)((b & 1) ? Ks0 : Ks1);
            half8v* Vd = (half8v*)((b & 1) ? Vs0 : Vs1);
            Kd[tid] = kr0;
            if (tid < 224) Kd[tid + 256] = kr1;
            Vd[tid] = vr0;
            Vd[tid + 256] = vr1;
            if (tid < 112) Vd[tid + 512] = vr2;
        }
        __syncthreads();
    }

    // write fused cond rows
#pragma unroll
    for (int t = 0; t < 3; ++t) {
        if (t < 2 || quad < 2) {
            half4v h = {(_Float16)oacc[t][0], (_Float16)oacc[t][1],
                        (_Float16)oacc[t][2], (_Float16)oacc[t][3]};
            *(half4v*)(Xh + (size_t)(HW + qrow0 + c) * C + head * HD + t * 16 + quad * 4) = h;
        }
    }
}

// ---------------------------------------------------------------------------
// O-projection f16 MFMA GEMM, B-tile staged in LDS (stride 328), A-fragments
// preloaded in one burst (latency hidden behind B staging), fused epilogue.
// ---------------------------------------------------------------------------
__global__ __launch_bounds__(256, 2) void gemm_oproj_f16(const _Float16* __restrict__ A,
                                                         const _Float16* __restrict__ BT,
                                                         const float* __restrict__ bo,
                                                         const float* __restrict__ wSum,
                                                         float* __restrict__ Out) {
    const int K = C;
    __shared__ _Float16 Bs[64 * 328];
    int tid = threadIdx.x;
    int n0 = blockIdx.x * 64;
    int lane = tid & 63, wave = tid >> 6;
    int m0 = blockIdx.y * 64 + wave * 16;
    int lr = lane & 15, kq = (lane >> 4) * 8;
    const _Float16* ap = A + (size_t)(m0 + lr) * K + kq;

    // preload all A-fragments (40 VGPRs) — one burst, hidden behind staging
    half8v afr[10];
#pragma unroll
    for (int i = 0; i < 10; ++i) afr[i] = *(const half8v*)(ap + i * 32);

    for (int i = tid; i < 64 * 40; i += 256) {
        int row = i / 40, c8 = i - row * 40;
        *(half8v*)&Bs[row * 328 + c8 * 8] =
            *(const half8v*)(BT + (size_t)(n0 + row) * K + c8 * 8);
    }
    __syncthreads();

    f32x4 acc0 = {0.f,0.f,0.f,0.f}, acc1 = acc0, acc2 = acc0, acc3 = acc0;
#pragma unroll
    for (int i = 0; i < 10; ++i) {
        int k0 = i * 32;
        half8v b0 = *(const half8v*)&Bs[(0 * 16 + lr) * 328 + k0 + kq];
        half8v b1 = *(const half8v*)&Bs[(1 * 16 + lr) * 328 + k0 + kq];
        half8v b2 = *(const half8v*)&Bs[(2 * 16 + lr) * 328 + k0 + kq];
        half8v b3 = *(const half8v*)&Bs[(3 * 16 + lr) * 328 + k0 + kq];
        acc0 = __builtin_amdgcn_mfma_f32_16x16x32_f16(afr[i], b0, acc0, 0, 0, 0);
        acc1 = __builtin_amdgcn_mfma_f32_16x16x32_f16(afr[i], b1, acc1, 0, 0, 0);
        acc2 = __builtin_amdgcn_mfma_f32_16x16x32_f16(afr[i], b2, acc2, 0, 0, 0);
        acc3 = __builtin_amdgcn_mfma_f32_16x16x32_f16(afr[i], b3, acc3, 0, 0, 0);
    }
    int rb = m0 + ((lane >> 4) << 2);
    f32x4 accs[4] = {acc0, acc1, acc2, acc3};
#pragma unroll
    for (int t = 0; t < 4; ++t) {
        int col = n0 + t * 16 + lr;
        float bv = bo[col];
#pragma unroll
        for (int r = 0; r < 4; ++r) {
            int row = rb + r;
            float v = accs[t][r];
            if (row < HW) {
                v += bv;
            } else {
                float ws = wSum[row - HW];
                v = (v + bv * ws) / (ws + 1e-6f);
            }
            Out[(size_t)row * C + col] = v;
        }
    }
}

// ---------------------------------------------------------------------------
// Launch: 4 dispatches.
// ---------------------------------------------------------------------------
extern "C" void kernel_launch(void* const* d_in, const int* in_sizes, int n_in,
                              void* d_out, int out_size, void* d_ws, size_t ws_size,
                              hipStream_t stream) {
    const float* hs   = (const float*)d_in[0];
    const float* ehs  = (const float*)d_in[1];
    const float* bbox = (const float*)d_in[2];
    const float* Wq   = (const float*)d_in[3];
    const float* Wk   = (const float*)d_in[4];
    const float* Wv   = (const float*)d_in[5];
    const float* Wo   = (const float*)d_in[6];
    const float* bo   = (const float*)d_in[7];
    float* out = (float*)d_out;

    float* wPh  = (float*)d_ws;                          // 9*4096
    float* wSum = wPh + (size_t)9 * HW;                  // 4096
    _Float16* hsH  = (_Float16*)(wSum + HW);             // 8192*320
    _Float16* ehsH = hsH + (size_t)2 * HW * C;           // 770*768
    _Float16* WqT  = ehsH + (size_t)NB * L * CX;         // 320*320
    _Float16* WkvT = WqT + (size_t)C * C;                // 640*768
    _Float16* WoT  = WkvT + (size_t)KVC * CX;            // 320*320
    _Float16* Khp  = WoT + (size_t)C * C;                // 80*80*KSTR
    _Float16* VTg  = Khp + (size_t)80 * KBH;             // 80*48*VSTR
    _Float16* Xh   = VTg + (size_t)80 * VBH;             // 8192*320

    prep_kernel<<<dim3(NPREP), 256, 0, stream>>>(bbox, hs, ehs, Wq, Wk, Wv, Wo,
                                                 wPh, wSum, hsH, ehsH, WqT, WkvT, WoT,
                                                 VTg, Khp);
    gemm_kv<<<dim3(KVC / 64, (NB * L + 63) / 64), 256, 0, stream>>>(ehsH, WkvT, Khp, VTg);
    attn_mfma<<<dim3(NH * 64), 256, 0, stream>>>(hsH, WqT, Khp, VTg, wPh, Xh);
    gemm_oproj_f16<<<dim3(C / 64, (2 * HW) / 64), 256, 0, stream>>>(Xh, WoT, bo, wSum, out);
}